// Round 19
// baseline (348.007 us; speedup 1.0000x reference)
//
#include <hip/hip_runtime.h>
#include <hip/hip_bf16.h>

#define N_NODES 100000
#define EMB 256
#define HID 64
#define N_REL 5
#define N_EDGES 3200000
#define BATCH 16384
#define NB 782                 // buckets of 128 dst nodes
#define NWG1 256               // scatter/hist WGs
#define CH 12500               // edges per WG chunk (256*12500 = 3.2M exact)
#define LSEG 640               // 128 nodes * 5 rels
#define NSEG (N_NODES * N_REL) // 500000
#define NSLOT (3 * BATCH)      // 49152 referenced-node slots
#define NSG 3072               // NSLOT / 16 slot-groups

typedef unsigned short u16;
typedef unsigned int u32;
typedef __attribute__((ext_vector_type(4))) float f32x4;
typedef __attribute__((ext_vector_type(8))) short short8;

__device__ __forceinline__ float bf2f(u16 u) {
    union { float f; u32 i; } v;
    v.i = ((u32)u) << 16;
    return v.f;
}
__device__ __forceinline__ u16 f2bf(float f) {
    union { float f; u32 i; } v;
    v.f = f;
    u32 r = v.i + 0x7fff + ((v.i >> 16) & 1);   // RNE
    return (u16)(r >> 16);
}
__device__ __forceinline__ short8 pack8(float4 a, float4 b) {
    short8 r;
    r[0] = (short)f2bf(a.x); r[1] = (short)f2bf(a.y);
    r[2] = (short)f2bf(a.z); r[3] = (short)f2bf(a.w);
    r[4] = (short)f2bf(b.x); r[5] = (short)f2bf(b.y);
    r[6] = (short)f2bf(b.z); r[7] = (short)f2bf(b.w);
    return r;
}

__device__ __forceinline__ void gload_lds16(const void* g, void* l) {
    __builtin_amdgcn_global_load_lds(
        (const __attribute__((address_space(1))) unsigned int*)g,
        (__attribute__((address_space(3))) unsigned int*)l, 16, 0, 0);
}

// ---------------------------------------------------------------------------
// K1: per-WG bucket histogram (deterministic chunks, no global atomics)
// ---------------------------------------------------------------------------
__global__ __launch_bounds__(256) void bucket_hist(const int* __restrict__ dst,
                                                   int* __restrict__ hist) {
    __shared__ int hl[NB];
    const int tid = threadIdx.x;
    for (int i = tid; i < NB; i += 256) hl[i] = 0;
    __syncthreads();
    const int w = blockIdx.x;
    const int s = w * CH, e = s + CH;
    for (int i = s + tid; i < e; i += 256)
        atomicAdd(&hl[dst[i] >> 7], 1);
    __syncthreads();
    for (int i = tid; i < NB; i += 256) hist[w * NB + i] = hl[i];
}

// ---------------------------------------------------------------------------
// K2a: per-bucket column scan over WGs (in-place hist -> base_local), btot out
// ---------------------------------------------------------------------------
__global__ void col_scan(int* __restrict__ hist, int* __restrict__ btot) {
    const int b = blockIdx.x;
    const int lane = threadIdx.x;
    int carry = 0;
    for (int c = 0; c < NWG1; c += 64) {
        int v = hist[(c + lane) * NB + b];
        int incl = v;
#pragma unroll
        for (int off = 1; off < 64; off <<= 1) {
            int t = __shfl_up(incl, off);
            if (lane >= off) incl += t;
        }
        hist[(c + lane) * NB + b] = carry + (incl - v);
        carry += __shfl(incl, 63);
    }
    if (lane == 0) btot[b] = carry;
}

// ---------------------------------------------------------------------------
// K2b: scan bucket totals -> bucket offsets (+ sentinels)
// ---------------------------------------------------------------------------
__global__ void btot_scan(const int* __restrict__ btot, int* __restrict__ boffs,
                          int* __restrict__ offs) {
    const int lane = threadIdx.x;
    int carry = 0;
    for (int c = 0; c < NB; c += 64) {
        int v = (c + lane < NB) ? btot[c + lane] : 0;
        int incl = v;
#pragma unroll
        for (int off = 1; off < 64; off <<= 1) {
            int t = __shfl_up(incl, off);
            if (lane >= off) incl += t;
        }
        if (c + lane < NB) boffs[c + lane] = carry + (incl - v);
        carry += __shfl(incl, 63);
    }
    if (lane == 0) {
        boffs[NB] = N_EDGES;
        offs[NSEG] = N_EDGES;   // global sentinel for offs-diff degree
    }
}

// ---------------------------------------------------------------------------
// K3: scatter packed keys into bucket-ordered array (LDS cursors -> bursts)
// key = src | ((ldst*5 + et) << 17)
// ---------------------------------------------------------------------------
__global__ __launch_bounds__(256) void bucket_scatter(
        const int* __restrict__ src, const int* __restrict__ dst,
        const int* __restrict__ et, const int* __restrict__ base,
        const int* __restrict__ boffs, u32* __restrict__ bucketed) {
    __shared__ int cur[NB];
    const int tid = threadIdx.x;
    const int w = blockIdx.x;
    for (int i = tid; i < NB; i += 256) cur[i] = boffs[i] + base[w * NB + i];
    __syncthreads();
    const int s = w * CH, e = s + CH;
    for (int i = s + tid; i < e; i += 256) {
        int d = dst[i];
        int b = d >> 7;
        u32 key = (u32)src[i] | ((u32)((d & 127) * 5 + et[i]) << 17);
        int pos = atomicAdd(&cur[b], 1);
        bucketed[pos] = key;
    }
}

// ---------------------------------------------------------------------------
// K4: within-bucket segment sort. One WG per bucket: LDS histogram of 640
// local segs -> wave scan -> global offs + LDS-cursor scatter.
// Output = plain src node id per edge, (dst,rel)-segment order.
// ---------------------------------------------------------------------------
__global__ __launch_bounds__(256) void seg_sort(
        const u32* __restrict__ keys, const int* __restrict__ boffs,
        int* __restrict__ offs, u32* __restrict__ ssrc) {
    __shared__ int cntl[LSEG];
    __shared__ int cur[LSEG];
    const int tid = threadIdx.x;
    const int b = blockIdx.x;
    const int s = boffs[b], e = boffs[b + 1];

    for (int i = tid; i < LSEG; i += 256) cntl[i] = 0;
    __syncthreads();
    for (int i = s + tid; i < e; i += 256)
        atomicAdd(&cntl[keys[i] >> 17], 1);
    __syncthreads();

    if (tid < 64) {   // wave 0: exclusive scan of 640 counts
        int carry = 0;
        for (int c = 0; c < LSEG; c += 64) {
            int v = cntl[c + tid];
            int incl = v;
#pragma unroll
            for (int off = 1; off < 64; off <<= 1) {
                int t = __shfl_up(incl, off);
                if (tid >= off) incl += t;
            }
            cur[c + tid] = carry + (incl - v);
            carry += __shfl(incl, 63);
        }
    }
    __syncthreads();

    const int segbase = b * LSEG;   // == (b*128)*5
    for (int i = tid; i < LSEG; i += 256)
        if (segbase + i < NSEG) offs[segbase + i] = s + cur[i];
    __syncthreads();

    for (int i = s + tid; i < e; i += 256) {
        u32 key = keys[i];
        int pos = s + atomicAdd(&cur[key >> 17], 1);
        ssrc[pos] = key & 0x1FFFF;
    }
}

// ---------------------------------------------------------------------------
// Pack weights: BT[j][k] = (j<320 ? W[j>>6][k][j&63] : root[k][j&63]) as bf16
// ---------------------------------------------------------------------------
__global__ void build_bt(const float* __restrict__ W, const float* __restrict__ root,
                         int K, u16* __restrict__ BT) {
    int idx = blockIdx.x * blockDim.x + threadIdx.x;
    if (idx >= 384 * K) return;
    int j = idx / K, k = idx - j * K;
    float v = (j < 320) ? W[((j >> 6) * K + k) * 64 + (j & 63)]
                        : root[k * 64 + (j & 63)];
    BT[idx] = f2bf(v);
}

// ---------------------------------------------------------------------------
// MFMA GEMM, DOUBLE-BUFFERED one-pass (R15-verified, best measured: 82 us):
//   h[100000][384] = A[100000][256](f32) x BT[384][256]^T
// ---------------------------------------------------------------------------
template <int K>
__global__ __launch_bounds__(512) void gemm_db(
        const float* __restrict__ Af, const u16* __restrict__ BT,
        u16* __restrict__ C) {
    __shared__ __align__(16) u16 Al[2][128 * 32];   // 8 KB x2
    __shared__ __align__(16) u16 Bl[2][384 * 32];   // 24 KB x2
    const int tid  = threadIdx.x;
    const int lane = tid & 63;
    const int w    = tid >> 6;
    const int m0 = blockIdx.x * 128;
    const int wr = (w >> 2) * 64;      // 0 / 64
    const int wc = (w & 3) * 96;       // 0 / 96 / 192 / 288
    const int l15 = lane & 15;
    const int lg  = lane >> 4;

    const int arow = tid >> 2;
    const int aq   = tid & 3;
    const int agrow = min(m0 + arow, N_NODES - 1);  // clamp (stores guarded)

    f32x4 acc[4][6];
#pragma unroll
    for (int i = 0; i < 4; ++i)
#pragma unroll
        for (int j = 0; j < 6; ++j) {
            f32x4 z = {0.f, 0.f, 0.f, 0.f};
            acc[i][j] = z;
        }

    // ---- prologue: fully stage buffer 0 (k0 = 0)
    {
#pragma unroll
        for (int j = 0; j < 3; ++j) {
            int c = (j * 8 + w) * 64 + lane;        // chunk id 0..1535
            int row = c >> 2, sub = c & 3;
            gload_lds16(BT + (size_t)row * K + ((sub ^ ((row >> 1) & 3)) * 8),
                        &Bl[0][(j * 8 + w) * 512]);
        }
        const float4* p = (const float4*)(Af + (size_t)agrow * K + aq * 8);
        float4 v0 = p[0], v1 = p[1];
        *(short8*)&Al[0][arow * 32 + ((aq ^ ((arow >> 1) & 3)) * 8)] = pack8(v0, v1);
    }
    __syncthreads();

    for (int k0 = 0; k0 < K; k0 += 32) {
        const int cur = (k0 >> 5) & 1;
        const bool more = (k0 + 32) < K;
        float4 va, vb;
        if (more) {
            // ---- issue next step's loads (latency overlaps this step's MFMA)
#pragma unroll
            for (int j = 0; j < 3; ++j) {
                int c = (j * 8 + w) * 64 + lane;
                int row = c >> 2, sub = c & 3;
                gload_lds16(BT + (size_t)row * K + k0 + 32 + ((sub ^ ((row >> 1) & 3)) * 8),
                            &Bl[cur ^ 1][(j * 8 + w) * 512]);
            }
            const float4* p = (const float4*)(Af + (size_t)agrow * K + k0 + 32 + aq * 8);
            va = p[0]; vb = p[1];
        }

        // ---- MFMA phase on buf[cur]: 24 MFMA per wave
        {
            short8 af[4], bf[6];
#pragma unroll
            for (int f = 0; f < 4; ++f) {
                int row = wr + f * 16 + l15;
                af[f] = *(const short8*)&Al[cur][row * 32 + ((lg ^ ((row >> 1) & 3)) * 8)];
            }
#pragma unroll
            for (int f = 0; f < 6; ++f) {
                int col = wc + f * 16 + l15;
                bf[f] = *(const short8*)&Bl[cur][col * 32 + ((lg ^ ((col >> 1) & 3)) * 8)];
            }
            // SWAPPED operands: acc[fm][fn][i] = C[wr+fm*16+l15][wc+fn*16+lg*4+i]
#pragma unroll
            for (int fm = 0; fm < 4; ++fm)
#pragma unroll
                for (int fn = 0; fn < 6; ++fn)
                    acc[fm][fn] = __builtin_amdgcn_mfma_f32_16x16x32_bf16(
                        bf[fn], af[fm], acc[fm][fn], 0, 0, 0);
        }

        if (more) {   // write-late: convert + ds_write next A (prev readers done)
            *(short8*)&Al[cur ^ 1][arow * 32 + ((aq ^ ((arow >> 1) & 3)) * 8)] = pack8(va, vb);
        }
        __syncthreads();   // drains B DMA (vmcnt) + A ds_write; protects cur
    }

    // ---- epilogue: stage 64-row halves in LDS (swizzled), stream out dense
    char* Cst = (char*)Bl;   // 48 KB staging: 64 rows x 384 cols bf16
#pragma unroll
    for (int half = 0; half < 2; ++half) {
        if ((w >> 2) == half) {
#pragma unroll
            for (int fm = 0; fm < 4; ++fm) {
                int row_l = fm * 16 + l15;                    // 0..63
#pragma unroll
                for (int fn = 0; fn < 6; ++fn) {
                    ushort4 p;
                    p.x = f2bf(acc[fm][fn][0]); p.y = f2bf(acc[fm][fn][1]);
                    p.z = f2bf(acc[fm][fn][2]); p.w = f2bf(acc[fm][fn][3]);
                    int colb  = (wc + fn * 16 + lg * 4) * 2;  // byte col (0..767)
                    int chunk = colb >> 4;                    // 0..47
                    int addr  = row_l * 768 + (((chunk ^ (row_l & 7)) << 4) | (colb & 15));
                    *(ushort4*)(Cst + addr) = p;
                }
            }
        }
        __syncthreads();
        // 3072 chunks of 16B; consecutive tids -> consecutive global addrs
#pragma unroll
        for (int it = 0; it < 6; ++it) {
            int idx = it * 512 + tid;
            int row_l = idx / 48;
            int chk = idx - row_l * 48;
            int r = m0 + half * 64 + row_l;
            if (r < N_NODES) {
                float4 v = *(const float4*)(Cst + row_l * 768 + ((chk ^ (row_l & 7)) << 4));
                *(float4*)(C + (size_t)r * 384 + chk * 8) = v;
            }
        }
        __syncthreads();
    }
}

// ---------------------------------------------------------------------------
// Layer-1 aggregate (readlane, 16-DEEP): one wave per dst node, lane = feat.
// Per 64-edge chunk: one coalesced ssrc load + per-lane reladd/weight via
// compare chain; 16-deep fixed unroll keeps ~16 gathers in flight per wave
// (was 8 — Little's law said in-flight bytes were the binding constraint).
// Over-processed tail edges are safe: clamped address + weight 0.
// ---------------------------------------------------------------------------
template <bool RELU>
__global__ __launch_bounds__(256) void agg_rl(
        const u16* __restrict__ h, const u32* __restrict__ ssrc,
        const int* __restrict__ offs, const float* __restrict__ bias,
        u16* __restrict__ out) {
    const int lane = threadIdx.x & 63;
    const int d = (blockIdx.x * blockDim.x + threadIdx.x) >> 6;
    if (d >= N_NODES) return;

    const int o0 = offs[d * 5 + 0], o1 = offs[d * 5 + 1], o2 = offs[d * 5 + 2];
    const int o3 = offs[d * 5 + 3], o4 = offs[d * 5 + 4], o5 = offs[d * 5 + 5];
    const float i0 = 1.f / (float)max(o1 - o0, 1);
    const float i1 = 1.f / (float)max(o2 - o1, 1);
    const float i2 = 1.f / (float)max(o3 - o2, 1);
    const float i3 = 1.f / (float)max(o4 - o3, 1);
    const float i4 = 1.f / (float)max(o5 - o4, 1);

    const u16* hl = h + lane;
    float acc0 = bf2f(h[(size_t)d * 384 + 320 + lane]) + bias[lane];
    float acc1 = 0.f, acc2 = 0.f, acc3 = 0.f;

    for (int base = o0; base < o5; base += 64) {
        const int idx = base + lane;
        const u32 s = ssrc[min(idx, o5 - 1)];             // coalesced, clamped
        u32 reladd;
        float wv;
        if (idx < o1)      { reladd = 0;   wv = i0; }
        else if (idx < o2) { reladd = 64;  wv = i1; }
        else if (idx < o3) { reladd = 128; wv = i2; }
        else if (idx < o4) { reladd = 192; wv = i3; }
        else               { reladd = 256; wv = i4; }
        if (idx >= o5) wv = 0.f;                          // tail contributes 0
        const u32 voff = s * 384u + reladd;
        const int m = min(64, o5 - base);
        for (int j = 0; j < m; j += 16) {
#pragma unroll
            for (int jj = 0; jj < 16; jj += 4) {
                int  offa = __builtin_amdgcn_readlane((int)voff, j + jj);
                int  wa_i = __builtin_amdgcn_readlane((int)__float_as_uint(wv), j + jj);
                int  offb = __builtin_amdgcn_readlane((int)voff, j + jj + 1);
                int  wb_i = __builtin_amdgcn_readlane((int)__float_as_uint(wv), j + jj + 1);
                int  offc = __builtin_amdgcn_readlane((int)voff, j + jj + 2);
                int  wc_i = __builtin_amdgcn_readlane((int)__float_as_uint(wv), j + jj + 2);
                int  offd = __builtin_amdgcn_readlane((int)voff, j + jj + 3);
                int  wd_i = __builtin_amdgcn_readlane((int)__float_as_uint(wv), j + jj + 3);
                acc0 += bf2f(hl[(u32)offa]) * __uint_as_float((u32)wa_i);
                acc1 += bf2f(hl[(u32)offb]) * __uint_as_float((u32)wb_i);
                acc2 += bf2f(hl[(u32)offc]) * __uint_as_float((u32)wc_i);
                acc3 += bf2f(hl[(u32)offd]) * __uint_as_float((u32)wd_i);
            }
        }
    }
    float acc = (acc0 + acc1) + (acc2 + acc3);
    if (RELU) acc = fmaxf(acc, 0.f);
    out[(size_t)d * 64 + lane] = f2bf(acc);
}

// ---------------------------------------------------------------------------
// Layer-2 FUSED aggregate+transform, SLOT-BASED (R13-VERIFIED, 16 slots):
//   semb[slot] = sum_r mean_r(x1)@W2_r + x1[n]@root2 + b2,  n = id(slot)
// ---------------------------------------------------------------------------
__global__ __launch_bounds__(1024) void agg_mm2(
        const u16* __restrict__ x1, const u32* __restrict__ ssrc,
        const int* __restrict__ offs,
        const int* __restrict__ bill, const int* __restrict__ u1,
        const int* __restrict__ u2,
        const float* __restrict__ W2, const float* __restrict__ root2,
        const float* __restrict__ b2, u16* __restrict__ semb) {
    __shared__ __align__(16) u16 WT[64 * 392];   // [out-col][k] padded, 49 KB
    __shared__ __align__(16) u16 Al[16 * 392];   // [slot][k] padded, 12.25 KB
    const int tid  = threadIdx.x;
    const int lane = tid & 63;
    const int wv   = tid >> 6;
    const int l15  = lane & 15;
    const int lg   = lane >> 4;

    // stage WT: Wcat[j][o] (j<320: W2, else root2) -> WT[o][j] bf16
    for (int i = tid; i < 384 * 64; i += 1024) {
        int j = i >> 6, o = i & 63;
        float v = (j < 320) ? W2[i] : root2[i - 320 * 64];
        WT[o * 392 + j] = f2bf(v);
    }
    __syncthreads();

    const float b2v = b2[(wv & 3) * 16 + l15];

    for (int g = blockIdx.x; g < NSG; g += gridDim.x) {
        const int slot = g * 16 + wv;
        const int n = (slot < BATCH) ? bill[slot]
                    : (slot < 2 * BATCH) ? u1[slot - BATCH]
                    : u2[slot - 2 * BATCH];
        int o[6];
#pragma unroll
        for (int r = 0; r < 6; ++r) o[r] = offs[n * 5 + r];
        Al[wv * 392 + 320 + lane] = x1[(size_t)n * 64 + lane];

        float am[5];
#pragma unroll
        for (int r = 0; r < 5; ++r) am[r] = 0.f;

        const int o0 = o[0], o5 = o[5];
        for (int base = o0; base < o5; base += 64) {
            // one coalesced chunk load covers ALL rel segments in [base,base+64)
            u32 voff = ssrc[min(base + lane, o5 - 1)] << 6;   // elem off src*64
#pragma unroll
            for (int r = 0; r < 5; ++r) {
                int jlo = max(o[r], base) - base;
                int jhi = min(o[r + 1], base + 64) - base;
                float s0 = 0.f, s1 = 0.f;
                int j = jlo;
                for (; j + 1 < jhi; j += 2) {
                    int oa = __builtin_amdgcn_readlane((int)voff, j);
                    int ob = __builtin_amdgcn_readlane((int)voff, j + 1);
                    s0 += bf2f(x1[(u32)oa + lane]);
                    s1 += bf2f(x1[(u32)ob + lane]);
                }
                if (j < jhi) {
                    int oa = __builtin_amdgcn_readlane((int)voff, j);
                    s0 += bf2f(x1[(u32)oa + lane]);
                }
                am[r] += s0 + s1;
            }
        }
#pragma unroll
        for (int r = 0; r < 5; ++r) {
            float inv = 1.f / (float)max(o[r + 1] - o[r], 1);
            Al[wv * 392 + r * 64 + lane] = f2bf(am[r] * inv);
        }
        __syncthreads();

        if (wv < 4) {   // [16,384]@[384,64]: wave wv owns 16-col slice
            f32x4 acc = {0.f, 0.f, 0.f, 0.f};
#pragma unroll
            for (int ks = 0; ks < 12; ++ks) {
                short8 af = *(const short8*)&Al[l15 * 392 + ks * 32 + lg * 8];
                short8 bf = *(const short8*)&WT[(wv * 16 + l15) * 392 + ks * 32 + lg * 8];
                acc = __builtin_amdgcn_mfma_f32_16x16x32_bf16(af, bf, acc, 0, 0, 0);
            }
            const int s0g = g * 16;
#pragma unroll
            for (int i = 0; i < 4; ++i)
                semb[(size_t)(s0g + lg * 4 + i) * 64 + wv * 16 + l15] =
                    f2bf(acc[i] + b2v);
        }
        __syncthreads();
    }
}

// ---------------------------------------------------------------------------
// Merge MLP + BCE/accuracy over compact semb[3*BATCH][64] (no node gather)
// ---------------------------------------------------------------------------
__global__ __launch_bounds__(256) void loss_kernel(
        const u16* __restrict__ semb,
        const float* __restrict__ w1, const float* __restrict__ b1,
        const float* __restrict__ w2, const float* __restrict__ b2,
        float* __restrict__ out) {
    __shared__ float Wl[128 * 64];
    __shared__ float red[2][4];
    for (int j = threadIdx.x; j < 128 * 16; j += 256)
        ((float4*)Wl)[j] = ((const float4*)w1)[j];
    __syncthreads();

    const int lane = threadIdx.x & 63;
    const int wv   = threadIdx.x >> 6;
    const int gw   = blockIdx.x * 4 + wv;
    const int nw   = gridDim.x * 4;

    const float bias1 = b1[lane];
    const float w2l   = w2[lane];
    const float bias2 = b2[0];

    float bce_acc = 0.f, corr_acc = 0.f;
    for (int s = gw; s < BATCH; s += nw) {
        const u16* xb  = semb + (size_t)s * 64;
        const u16* xu1 = semb + (size_t)(BATCH + s) * 64;
        const u16* xu2 = semb + (size_t)(2 * BATCH + s) * 64;
        float hb = bias1, h1 = 0.f, h2 = 0.f;
#pragma unroll 8
        for (int i = 0; i < 64; ++i) {
            float wb = Wl[i * 64 + lane];
            float wu = Wl[(64 + i) * 64 + lane];
            hb += bf2f(xb[i]) * wb;
            h1 += bf2f(xu1[i]) * wu;
            h2 += bf2f(xu2[i]) * wu;
        }
        float p1 = fmaxf(hb + h1, 0.f) * w2l;
        float p2 = fmaxf(hb + h2, 0.f) * w2l;
#pragma unroll
        for (int off = 32; off > 0; off >>= 1) {
            p1 += __shfl_down(p1, off);
            p2 += __shfl_down(p2, off);
        }
        if (lane == 0) {
            float z1 = p1 + bias2;   // target 1
            float z2 = p2 + bias2;   // target 0
            bce_acc += fmaxf(z1, 0.f) - z1 + log1pf(expf(-fabsf(z1)));
            bce_acc += fmaxf(z2, 0.f)      + log1pf(expf(-fabsf(z2)));
            corr_acc += (z1 > 0.f) ? 1.f : 0.f;
            corr_acc += (z2 > 0.f) ? 0.f : 1.f;
        }
    }
    if (lane == 0) { red[0][wv] = bce_acc; red[1][wv] = corr_acc; }
    __syncthreads();
    if (threadIdx.x == 0) {
        const float scale = 1.f / (2.f * BATCH);
        atomicAdd(&out[0], (red[0][0] + red[0][1] + red[0][2] + red[0][3]) * scale);
        atomicAdd(&out[1], (red[1][0] + red[1][1] + red[1][2] + red[1][3]) * scale);
    }
}

// ---------------------------------------------------------------------------
extern "C" void kernel_launch(void* const* d_in, const int* in_sizes, int n_in,
                              void* d_out, int out_size, void* d_ws, size_t ws_size,
                              hipStream_t stream) {
    const int*   bill  = (const int*)d_in[0];
    const int*   u1    = (const int*)d_in[1];
    const int*   u2    = (const int*)d_in[2];
    const int*   ei    = (const int*)d_in[3];
    const int*   et    = (const int*)d_in[4];
    const float* uf    = (const float*)d_in[5];
    const float* W1    = (const float*)d_in[6];
    const float* root1 = (const float*)d_in[7];
    const float* b1    = (const float*)d_in[8];
    const float* W2    = (const float*)d_in[9];
    const float* root2 = (const float*)d_in[10];
    const float* b2    = (const float*)d_in[11];
    const float* m1w   = (const float*)d_in[12];
    const float* m1b   = (const float*)d_in[13];
    const float* m2w   = (const float*)d_in[14];
    const float* m2b   = (const float*)d_in[15];
    float* out = (float*)d_out;

    // ws layout (peak 105,452,816 B < proven 106,400,000 B):
    //   0           h_all     76,800,000   [100000][384] bf16 (L1);
    //                                      semb [49152][64] aliases after agg_rl
    //  76,800,000   ssrc      12,800,000   u32 src per edge, segment order
    //  89,600,000   bucketed  12,800,000   u32 keys (dead after seg_sort;
    //                                      xbuf = x1 aliases here)
    // 102,400,000   hist         800,768   [256][782] int
    // 103,200,768   btot           3,128
    // 103,203,896   boffs          3,132   (783 ints)
    // 103,207,040   offs       2,000,004   (NSEG+1 ints)
    // 105,207,056   BT1          196,608
    char* ws = (char*)d_ws;
    u16* h_all    = (u16*)(ws);
    u16* semb     = (u16*)(ws);              // alias: valid after agg_rl
    u32* ssrc     = (u32*)(ws + 76800000);
    u32* bucketed = (u32*)(ws + 89600000);
    u16* xbuf     = (u16*)(ws + 89600000);   // alias: valid after seg_sort
    int* hist     = (int*)(ws + 102400000);
    int* btot     = (int*)(ws + 103200768);
    int* boffs    = (int*)(ws + 103203896);
    int* offs     = (int*)(ws + 103207040);
    u16* BT1      = (u16*)(ws + 105207056);
    if (ws_size < 105452816) return;  // fail visibly

    const int* src = ei;
    const int* dst = ei + N_EDGES;

    hipMemsetAsync(d_out, 0, 2 * sizeof(float), stream);

    // ---- two-level bucket sort into (dst,rel) segment order
    bucket_hist<<<NWG1, 256, 0, stream>>>(dst, hist);
    col_scan<<<NB, 64, 0, stream>>>(hist, btot);
    btot_scan<<<1, 64, 0, stream>>>(btot, boffs, offs);
    bucket_scatter<<<NWG1, 256, 0, stream>>>(src, dst, et, hist, boffs, bucketed);
    seg_sort<<<NB, 256, 0, stream>>>(bucketed, boffs, offs, ssrc);

    // ---- pack layer-1 weights to BT1 (bf16, [384][256])
    build_bt<<<(384 * EMB + 255) / 256, 256, 0, stream>>>(W1, root1, EMB, BT1);

    // ---- Layer 1: transform-first (256 -> 384, double-buffered), aggregate
    gemm_db<EMB><<<782, 512, 0, stream>>>(uf, BT1, h_all);
    agg_rl<true><<<25000, 256, 0, stream>>>(h_all, ssrc, offs, b1, xbuf);

    // ---- Layer 2: slot-based aggregate-first (only nodes the loss reads)
    agg_mm2<<<1024, 1024, 0, stream>>>(xbuf, ssrc, offs, bill, u1, u2,
                                       W2, root2, b2, semb);

    // ---- Merge MLP + BCE + accuracy
    loss_kernel<<<1024, 256, 0, stream>>>(semb, m1w, m1b, m2w, m2b, out);
}

// Round 20
// 326.524 us; speedup vs baseline: 1.0658x; 1.0658x over previous
//
#include <hip/hip_runtime.h>
#include <hip/hip_bf16.h>

#define N_NODES 100000
#define EMB 256
#define HID 64
#define N_REL 5
#define N_EDGES 3200000
#define BATCH 16384
#define NB 782                 // buckets of 128 dst nodes
#define NWG1 256               // scatter/hist WGs
#define CH 12500               // edges per WG chunk (256*12500 = 3.2M exact)
#define LSEG 640               // 128 nodes * 5 rels
#define NSEG (N_NODES * N_REL) // 500000
#define NSLOT (3 * BATCH)      // 49152 referenced-node slots
#define NSG 3072               // NSLOT / 16 slot-groups

typedef unsigned short u16;
typedef unsigned int u32;
typedef __attribute__((ext_vector_type(4))) float f32x4;
typedef __attribute__((ext_vector_type(8))) short short8;

__device__ __forceinline__ float bf2f(u16 u) {
    union { float f; u32 i; } v;
    v.i = ((u32)u) << 16;
    return v.f;
}
__device__ __forceinline__ u16 f2bf(float f) {
    union { float f; u32 i; } v;
    v.f = f;
    u32 r = v.i + 0x7fff + ((v.i >> 16) & 1);   // RNE
    return (u16)(r >> 16);
}
__device__ __forceinline__ short8 pack8(float4 a, float4 b) {
    short8 r;
    r[0] = (short)f2bf(a.x); r[1] = (short)f2bf(a.y);
    r[2] = (short)f2bf(a.z); r[3] = (short)f2bf(a.w);
    r[4] = (short)f2bf(b.x); r[5] = (short)f2bf(b.y);
    r[6] = (short)f2bf(b.z); r[7] = (short)f2bf(b.w);
    return r;
}

__device__ __forceinline__ void gload_lds16(const void* g, void* l) {
    __builtin_amdgcn_global_load_lds(
        (const __attribute__((address_space(1))) unsigned int*)g,
        (__attribute__((address_space(3))) unsigned int*)l, 16, 0, 0);
}

// ---------------------------------------------------------------------------
// K1: per-WG bucket histogram (deterministic chunks, no global atomics)
// ---------------------------------------------------------------------------
__global__ __launch_bounds__(256) void bucket_hist(const int* __restrict__ dst,
                                                   int* __restrict__ hist) {
    __shared__ int hl[NB];
    const int tid = threadIdx.x;
    for (int i = tid; i < NB; i += 256) hl[i] = 0;
    __syncthreads();
    const int w = blockIdx.x;
    const int s = w * CH, e = s + CH;
    for (int i = s + tid; i < e; i += 256)
        atomicAdd(&hl[dst[i] >> 7], 1);
    __syncthreads();
    for (int i = tid; i < NB; i += 256) hist[w * NB + i] = hl[i];
}

// ---------------------------------------------------------------------------
// K2a: per-bucket column scan over WGs (in-place hist -> base_local), btot out
// ---------------------------------------------------------------------------
__global__ void col_scan(int* __restrict__ hist, int* __restrict__ btot) {
    const int b = blockIdx.x;
    const int lane = threadIdx.x;
    int carry = 0;
    for (int c = 0; c < NWG1; c += 64) {
        int v = hist[(c + lane) * NB + b];
        int incl = v;
#pragma unroll
        for (int off = 1; off < 64; off <<= 1) {
            int t = __shfl_up(incl, off);
            if (lane >= off) incl += t;
        }
        hist[(c + lane) * NB + b] = carry + (incl - v);
        carry += __shfl(incl, 63);
    }
    if (lane == 0) btot[b] = carry;
}

// ---------------------------------------------------------------------------
// K2b: scan bucket totals -> bucket offsets (+ sentinels)
// ---------------------------------------------------------------------------
__global__ void btot_scan(const int* __restrict__ btot, int* __restrict__ boffs,
                          int* __restrict__ offs) {
    const int lane = threadIdx.x;
    int carry = 0;
    for (int c = 0; c < NB; c += 64) {
        int v = (c + lane < NB) ? btot[c + lane] : 0;
        int incl = v;
#pragma unroll
        for (int off = 1; off < 64; off <<= 1) {
            int t = __shfl_up(incl, off);
            if (lane >= off) incl += t;
        }
        if (c + lane < NB) boffs[c + lane] = carry + (incl - v);
        carry += __shfl(incl, 63);
    }
    if (lane == 0) {
        boffs[NB] = N_EDGES;
        offs[NSEG] = N_EDGES;   // global sentinel for offs-diff degree
    }
}

// ---------------------------------------------------------------------------
// K3: scatter packed keys into bucket-ordered array (LDS cursors -> bursts)
// key = src | ((ldst*5 + et) << 17)
// ---------------------------------------------------------------------------
__global__ __launch_bounds__(256) void bucket_scatter(
        const int* __restrict__ src, const int* __restrict__ dst,
        const int* __restrict__ et, const int* __restrict__ base,
        const int* __restrict__ boffs, u32* __restrict__ bucketed) {
    __shared__ int cur[NB];
    const int tid = threadIdx.x;
    const int w = blockIdx.x;
    for (int i = tid; i < NB; i += 256) cur[i] = boffs[i] + base[w * NB + i];
    __syncthreads();
    const int s = w * CH, e = s + CH;
    for (int i = s + tid; i < e; i += 256) {
        int d = dst[i];
        int b = d >> 7;
        u32 key = (u32)src[i] | ((u32)((d & 127) * 5 + et[i]) << 17);
        int pos = atomicAdd(&cur[b], 1);
        bucketed[pos] = key;
    }
}

// ---------------------------------------------------------------------------
// K4: within-bucket segment sort. One WG per bucket: LDS histogram of 640
// local segs -> wave scan -> global offs + LDS-cursor scatter.
// Output = plain src node id per edge, (dst,rel)-segment order.
// ---------------------------------------------------------------------------
__global__ __launch_bounds__(256) void seg_sort(
        const u32* __restrict__ keys, const int* __restrict__ boffs,
        int* __restrict__ offs, u32* __restrict__ ssrc) {
    __shared__ int cntl[LSEG];
    __shared__ int cur[LSEG];
    const int tid = threadIdx.x;
    const int b = blockIdx.x;
    const int s = boffs[b], e = boffs[b + 1];

    for (int i = tid; i < LSEG; i += 256) cntl[i] = 0;
    __syncthreads();
    for (int i = s + tid; i < e; i += 256)
        atomicAdd(&cntl[keys[i] >> 17], 1);
    __syncthreads();

    if (tid < 64) {   // wave 0: exclusive scan of 640 counts
        int carry = 0;
        for (int c = 0; c < LSEG; c += 64) {
            int v = cntl[c + tid];
            int incl = v;
#pragma unroll
            for (int off = 1; off < 64; off <<= 1) {
                int t = __shfl_up(incl, off);
                if (tid >= off) incl += t;
            }
            cur[c + tid] = carry + (incl - v);
            carry += __shfl(incl, 63);
        }
    }
    __syncthreads();

    const int segbase = b * LSEG;   // == (b*128)*5
    for (int i = tid; i < LSEG; i += 256)
        if (segbase + i < NSEG) offs[segbase + i] = s + cur[i];
    __syncthreads();

    for (int i = s + tid; i < e; i += 256) {
        u32 key = keys[i];
        int pos = s + atomicAdd(&cur[key >> 17], 1);
        ssrc[pos] = key & 0x1FFFF;
    }
}

// ---------------------------------------------------------------------------
// Pack weights: BT[j][k] = (j<320 ? W[j>>6][k][j&63] : root[k][j&63]) as bf16
// ---------------------------------------------------------------------------
__global__ void build_bt(const float* __restrict__ W, const float* __restrict__ root,
                         int K, u16* __restrict__ BT) {
    int idx = blockIdx.x * blockDim.x + threadIdx.x;
    if (idx >= 384 * K) return;
    int j = idx / K, k = idx - j * K;
    float v = (j < 320) ? W[((j >> 6) * K + k) * 64 + (j & 63)]
                        : root[k * 64 + (j & 63)];
    BT[idx] = f2bf(v);
}

// ---------------------------------------------------------------------------
// MFMA GEMM, DOUBLE-BUFFERED one-pass (R15-verified, best measured: 82 us):
//   h[100000][384] = A[100000][256](f32) x BT[384][256]^T
// ---------------------------------------------------------------------------
template <int K>
__global__ __launch_bounds__(512) void gemm_db(
        const float* __restrict__ Af, const u16* __restrict__ BT,
        u16* __restrict__ C) {
    __shared__ __align__(16) u16 Al[2][128 * 32];   // 8 KB x2
    __shared__ __align__(16) u16 Bl[2][384 * 32];   // 24 KB x2
    const int tid  = threadIdx.x;
    const int lane = tid & 63;
    const int w    = tid >> 6;
    const int m0 = blockIdx.x * 128;
    const int wr = (w >> 2) * 64;      // 0 / 64
    const int wc = (w & 3) * 96;       // 0 / 96 / 192 / 288
    const int l15 = lane & 15;
    const int lg  = lane >> 4;

    const int arow = tid >> 2;
    const int aq   = tid & 3;
    const int agrow = min(m0 + arow, N_NODES - 1);  // clamp (stores guarded)

    f32x4 acc[4][6];
#pragma unroll
    for (int i = 0; i < 4; ++i)
#pragma unroll
        for (int j = 0; j < 6; ++j) {
            f32x4 z = {0.f, 0.f, 0.f, 0.f};
            acc[i][j] = z;
        }

    // ---- prologue: fully stage buffer 0 (k0 = 0)
    {
#pragma unroll
        for (int j = 0; j < 3; ++j) {
            int c = (j * 8 + w) * 64 + lane;        // chunk id 0..1535
            int row = c >> 2, sub = c & 3;
            gload_lds16(BT + (size_t)row * K + ((sub ^ ((row >> 1) & 3)) * 8),
                        &Bl[0][(j * 8 + w) * 512]);
        }
        const float4* p = (const float4*)(Af + (size_t)agrow * K + aq * 8);
        float4 v0 = p[0], v1 = p[1];
        *(short8*)&Al[0][arow * 32 + ((aq ^ ((arow >> 1) & 3)) * 8)] = pack8(v0, v1);
    }
    __syncthreads();

    for (int k0 = 0; k0 < K; k0 += 32) {
        const int cur = (k0 >> 5) & 1;
        const bool more = (k0 + 32) < K;
        float4 va, vb;
        if (more) {
            // ---- issue next step's loads (latency overlaps this step's MFMA)
#pragma unroll
            for (int j = 0; j < 3; ++j) {
                int c = (j * 8 + w) * 64 + lane;
                int row = c >> 2, sub = c & 3;
                gload_lds16(BT + (size_t)row * K + k0 + 32 + ((sub ^ ((row >> 1) & 3)) * 8),
                            &Bl[cur ^ 1][(j * 8 + w) * 512]);
            }
            const float4* p = (const float4*)(Af + (size_t)agrow * K + k0 + 32 + aq * 8);
            va = p[0]; vb = p[1];
        }

        // ---- MFMA phase on buf[cur]: 24 MFMA per wave
        {
            short8 af[4], bf[6];
#pragma unroll
            for (int f = 0; f < 4; ++f) {
                int row = wr + f * 16 + l15;
                af[f] = *(const short8*)&Al[cur][row * 32 + ((lg ^ ((row >> 1) & 3)) * 8)];
            }
#pragma unroll
            for (int f = 0; f < 6; ++f) {
                int col = wc + f * 16 + l15;
                bf[f] = *(const short8*)&Bl[cur][col * 32 + ((lg ^ ((col >> 1) & 3)) * 8)];
            }
            // SWAPPED operands: acc[fm][fn][i] = C[wr+fm*16+l15][wc+fn*16+lg*4+i]
#pragma unroll
            for (int fm = 0; fm < 4; ++fm)
#pragma unroll
                for (int fn = 0; fn < 6; ++fn)
                    acc[fm][fn] = __builtin_amdgcn_mfma_f32_16x16x32_bf16(
                        bf[fn], af[fm], acc[fm][fn], 0, 0, 0);
        }

        if (more) {   // write-late: convert + ds_write next A (prev readers done)
            *(short8*)&Al[cur ^ 1][arow * 32 + ((aq ^ ((arow >> 1) & 3)) * 8)] = pack8(va, vb);
        }
        __syncthreads();   // drains B DMA (vmcnt) + A ds_write; protects cur
    }

    // ---- epilogue: stage 64-row halves in LDS (swizzled), stream out dense
    char* Cst = (char*)Bl;   // 48 KB staging: 64 rows x 384 cols bf16
#pragma unroll
    for (int half = 0; half < 2; ++half) {
        if ((w >> 2) == half) {
#pragma unroll
            for (int fm = 0; fm < 4; ++fm) {
                int row_l = fm * 16 + l15;                    // 0..63
#pragma unroll
                for (int fn = 0; fn < 6; ++fn) {
                    ushort4 p;
                    p.x = f2bf(acc[fm][fn][0]); p.y = f2bf(acc[fm][fn][1]);
                    p.z = f2bf(acc[fm][fn][2]); p.w = f2bf(acc[fm][fn][3]);
                    int colb  = (wc + fn * 16 + lg * 4) * 2;  // byte col (0..767)
                    int chunk = colb >> 4;                    // 0..47
                    int addr  = row_l * 768 + (((chunk ^ (row_l & 7)) << 4) | (colb & 15));
                    *(ushort4*)(Cst + addr) = p;
                }
            }
        }
        __syncthreads();
        // 3072 chunks of 16B; consecutive tids -> consecutive global addrs
#pragma unroll
        for (int it = 0; it < 6; ++it) {
            int idx = it * 512 + tid;
            int row_l = idx / 48;
            int chk = idx - row_l * 48;
            int r = m0 + half * 64 + row_l;
            if (r < N_NODES) {
                float4 v = *(const float4*)(Cst + row_l * 768 + ((chk ^ (row_l & 7)) << 4));
                *(float4*)(C + (size_t)r * 384 + chk * 8) = v;
            }
        }
        __syncthreads();
    }
}

// ---------------------------------------------------------------------------
// Layer-1 aggregate (readlane, R13/R18-VERIFIED 8-deep): one wave per dst
// node, lane = feature. Per 64-edge chunk: one coalesced ssrc load + per-lane
// reladd/weight via compare chain; 8-deep fixed unroll (best of 3 variants:
// subrange=118us, 16-deep>=same, 8-deep=75us).
// ---------------------------------------------------------------------------
template <bool RELU>
__global__ __launch_bounds__(256) void agg_rl(
        const u16* __restrict__ h, const u32* __restrict__ ssrc,
        const int* __restrict__ offs, const float* __restrict__ bias,
        u16* __restrict__ out) {
    const int lane = threadIdx.x & 63;
    const int d = (blockIdx.x * blockDim.x + threadIdx.x) >> 6;
    if (d >= N_NODES) return;

    const int o0 = offs[d * 5 + 0], o1 = offs[d * 5 + 1], o2 = offs[d * 5 + 2];
    const int o3 = offs[d * 5 + 3], o4 = offs[d * 5 + 4], o5 = offs[d * 5 + 5];
    const float i0 = 1.f / (float)max(o1 - o0, 1);
    const float i1 = 1.f / (float)max(o2 - o1, 1);
    const float i2 = 1.f / (float)max(o3 - o2, 1);
    const float i3 = 1.f / (float)max(o4 - o3, 1);
    const float i4 = 1.f / (float)max(o5 - o4, 1);

    const u16* hl = h + lane;
    float acc0 = bf2f(h[(size_t)d * 384 + 320 + lane]) + bias[lane];
    float acc1 = 0.f;

    for (int base = o0; base < o5; base += 64) {
        const int idx = base + lane;
        const u32 s = ssrc[min(idx, o5 - 1)];             // coalesced, clamped
        u32 reladd;
        float wv;
        if (idx < o1)      { reladd = 0;   wv = i0; }
        else if (idx < o2) { reladd = 64;  wv = i1; }
        else if (idx < o3) { reladd = 128; wv = i2; }
        else if (idx < o4) { reladd = 192; wv = i3; }
        else               { reladd = 256; wv = i4; }
        if (idx >= o5) wv = 0.f;                          // tail contributes 0
        const u32 voff = s * 384u + reladd;
        const int m = min(64, o5 - base);
        for (int j = 0; j < m; j += 8) {
#pragma unroll
            for (int jj = 0; jj < 8; jj += 2) {
                int  offa = __builtin_amdgcn_readlane((int)voff, j + jj);
                int  wa_i = __builtin_amdgcn_readlane((int)__float_as_uint(wv), j + jj);
                int  offb = __builtin_amdgcn_readlane((int)voff, j + jj + 1);
                int  wb_i = __builtin_amdgcn_readlane((int)__float_as_uint(wv), j + jj + 1);
                acc0 += bf2f(hl[(u32)offa]) * __uint_as_float((u32)wa_i);
                acc1 += bf2f(hl[(u32)offb]) * __uint_as_float((u32)wb_i);
            }
        }
    }
    float acc = acc0 + acc1;
    if (RELU) acc = fmaxf(acc, 0.f);
    out[(size_t)d * 64 + lane] = f2bf(acc);
}

// ---------------------------------------------------------------------------
// Layer-2 FUSED aggregate+transform, SLOT-BASED (R13-VERIFIED, 16 slots):
//   semb[slot] = sum_r mean_r(x1)@W2_r + x1[n]@root2 + b2,  n = id(slot)
// ---------------------------------------------------------------------------
__global__ __launch_bounds__(1024) void agg_mm2(
        const u16* __restrict__ x1, const u32* __restrict__ ssrc,
        const int* __restrict__ offs,
        const int* __restrict__ bill, const int* __restrict__ u1,
        const int* __restrict__ u2,
        const float* __restrict__ W2, const float* __restrict__ root2,
        const float* __restrict__ b2, u16* __restrict__ semb) {
    __shared__ __align__(16) u16 WT[64 * 392];   // [out-col][k] padded, 49 KB
    __shared__ __align__(16) u16 Al[16 * 392];   // [slot][k] padded, 12.25 KB
    const int tid  = threadIdx.x;
    const int lane = tid & 63;
    const int wv   = tid >> 6;
    const int l15  = lane & 15;
    const int lg   = lane >> 4;

    // stage WT: Wcat[j][o] (j<320: W2, else root2) -> WT[o][j] bf16
    for (int i = tid; i < 384 * 64; i += 1024) {
        int j = i >> 6, o = i & 63;
        float v = (j < 320) ? W2[i] : root2[i - 320 * 64];
        WT[o * 392 + j] = f2bf(v);
    }
    __syncthreads();

    const float b2v = b2[(wv & 3) * 16 + l15];

    for (int g = blockIdx.x; g < NSG; g += gridDim.x) {
        const int slot = g * 16 + wv;
        const int n = (slot < BATCH) ? bill[slot]
                    : (slot < 2 * BATCH) ? u1[slot - BATCH]
                    : u2[slot - 2 * BATCH];
        int o[6];
#pragma unroll
        for (int r = 0; r < 6; ++r) o[r] = offs[n * 5 + r];
        Al[wv * 392 + 320 + lane] = x1[(size_t)n * 64 + lane];

        float am[5];
#pragma unroll
        for (int r = 0; r < 5; ++r) am[r] = 0.f;

        const int o0 = o[0], o5 = o[5];
        for (int base = o0; base < o5; base += 64) {
            // one coalesced chunk load covers ALL rel segments in [base,base+64)
            u32 voff = ssrc[min(base + lane, o5 - 1)] << 6;   // elem off src*64
#pragma unroll
            for (int r = 0; r < 5; ++r) {
                int jlo = max(o[r], base) - base;
                int jhi = min(o[r + 1], base + 64) - base;
                float s0 = 0.f, s1 = 0.f;
                int j = jlo;
                for (; j + 1 < jhi; j += 2) {
                    int oa = __builtin_amdgcn_readlane((int)voff, j);
                    int ob = __builtin_amdgcn_readlane((int)voff, j + 1);
                    s0 += bf2f(x1[(u32)oa + lane]);
                    s1 += bf2f(x1[(u32)ob + lane]);
                }
                if (j < jhi) {
                    int oa = __builtin_amdgcn_readlane((int)voff, j);
                    s0 += bf2f(x1[(u32)oa + lane]);
                }
                am[r] += s0 + s1;
            }
        }
#pragma unroll
        for (int r = 0; r < 5; ++r) {
            float inv = 1.f / (float)max(o[r + 1] - o[r], 1);
            Al[wv * 392 + r * 64 + lane] = f2bf(am[r] * inv);
        }
        __syncthreads();

        if (wv < 4) {   // [16,384]@[384,64]: wave wv owns 16-col slice
            f32x4 acc = {0.f, 0.f, 0.f, 0.f};
#pragma unroll
            for (int ks = 0; ks < 12; ++ks) {
                short8 af = *(const short8*)&Al[l15 * 392 + ks * 32 + lg * 8];
                short8 bf = *(const short8*)&WT[(wv * 16 + l15) * 392 + ks * 32 + lg * 8];
                acc = __builtin_amdgcn_mfma_f32_16x16x32_bf16(af, bf, acc, 0, 0, 0);
            }
            const int s0g = g * 16;
#pragma unroll
            for (int i = 0; i < 4; ++i)
                semb[(size_t)(s0g + lg * 4 + i) * 64 + wv * 16 + l15] =
                    f2bf(acc[i] + b2v);
        }
        __syncthreads();
    }
}

// ---------------------------------------------------------------------------
// Merge MLP + BCE/accuracy over compact semb[3*BATCH][64] (no node gather)
// ---------------------------------------------------------------------------
__global__ __launch_bounds__(256) void loss_kernel(
        const u16* __restrict__ semb,
        const float* __restrict__ w1, const float* __restrict__ b1,
        const float* __restrict__ w2, const float* __restrict__ b2,
        float* __restrict__ out) {
    __shared__ float Wl[128 * 64];
    __shared__ float red[2][4];
    for (int j = threadIdx.x; j < 128 * 16; j += 256)
        ((float4*)Wl)[j] = ((const float4*)w1)[j];
    __syncthreads();

    const int lane = threadIdx.x & 63;
    const int wv   = threadIdx.x >> 6;
    const int gw   = blockIdx.x * 4 + wv;
    const int nw   = gridDim.x * 4;

    const float bias1 = b1[lane];
    const float w2l   = w2[lane];
    const float bias2 = b2[0];

    float bce_acc = 0.f, corr_acc = 0.f;
    for (int s = gw; s < BATCH; s += nw) {
        const u16* xb  = semb + (size_t)s * 64;
        const u16* xu1 = semb + (size_t)(BATCH + s) * 64;
        const u16* xu2 = semb + (size_t)(2 * BATCH + s) * 64;
        float hb = bias1, h1 = 0.f, h2 = 0.f;
#pragma unroll 8
        for (int i = 0; i < 64; ++i) {
            float wb = Wl[i * 64 + lane];
            float wu = Wl[(64 + i) * 64 + lane];
            hb += bf2f(xb[i]) * wb;
            h1 += bf2f(xu1[i]) * wu;
            h2 += bf2f(xu2[i]) * wu;
        }
        float p1 = fmaxf(hb + h1, 0.f) * w2l;
        float p2 = fmaxf(hb + h2, 0.f) * w2l;
#pragma unroll
        for (int off = 32; off > 0; off >>= 1) {
            p1 += __shfl_down(p1, off);
            p2 += __shfl_down(p2, off);
        }
        if (lane == 0) {
            float z1 = p1 + bias2;   // target 1
            float z2 = p2 + bias2;   // target 0
            bce_acc += fmaxf(z1, 0.f) - z1 + log1pf(expf(-fabsf(z1)));
            bce_acc += fmaxf(z2, 0.f)      + log1pf(expf(-fabsf(z2)));
            corr_acc += (z1 > 0.f) ? 1.f : 0.f;
            corr_acc += (z2 > 0.f) ? 0.f : 1.f;
        }
    }
    if (lane == 0) { red[0][wv] = bce_acc; red[1][wv] = corr_acc; }
    __syncthreads();
    if (threadIdx.x == 0) {
        const float scale = 1.f / (2.f * BATCH);
        atomicAdd(&out[0], (red[0][0] + red[0][1] + red[0][2] + red[0][3]) * scale);
        atomicAdd(&out[1], (red[1][0] + red[1][1] + red[1][2] + red[1][3]) * scale);
    }
}

// ---------------------------------------------------------------------------
extern "C" void kernel_launch(void* const* d_in, const int* in_sizes, int n_in,
                              void* d_out, int out_size, void* d_ws, size_t ws_size,
                              hipStream_t stream) {
    const int*   bill  = (const int*)d_in[0];
    const int*   u1    = (const int*)d_in[1];
    const int*   u2    = (const int*)d_in[2];
    const int*   ei    = (const int*)d_in[3];
    const int*   et    = (const int*)d_in[4];
    const float* uf    = (const float*)d_in[5];
    const float* W1    = (const float*)d_in[6];
    const float* root1 = (const float*)d_in[7];
    const float* b1    = (const float*)d_in[8];
    const float* W2    = (const float*)d_in[9];
    const float* root2 = (const float*)d_in[10];
    const float* b2    = (const float*)d_in[11];
    const float* m1w   = (const float*)d_in[12];
    const float* m1b   = (const float*)d_in[13];
    const float* m2w   = (const float*)d_in[14];
    const float* m2b   = (const float*)d_in[15];
    float* out = (float*)d_out;

    // ws layout (peak 105,452,816 B < proven 106,400,000 B):
    //   0           h_all     76,800,000   [100000][384] bf16 (L1);
    //                                      semb [49152][64] aliases after agg_rl
    //  76,800,000   ssrc      12,800,000   u32 src per edge, segment order
    //  89,600,000   bucketed  12,800,000   u32 keys (dead after seg_sort;
    //                                      xbuf = x1 aliases here)
    // 102,400,000   hist         800,768   [256][782] int
    // 103,200,768   btot           3,128
    // 103,203,896   boffs          3,132   (783 ints)
    // 103,207,040   offs       2,000,004   (NSEG+1 ints)
    // 105,207,056   BT1          196,608
    char* ws = (char*)d_ws;
    u16* h_all    = (u16*)(ws);
    u16* semb     = (u16*)(ws);              // alias: valid after agg_rl
    u32* ssrc     = (u32*)(ws + 76800000);
    u32* bucketed = (u32*)(ws + 89600000);
    u16* xbuf     = (u16*)(ws + 89600000);   // alias: valid after seg_sort
    int* hist     = (int*)(ws + 102400000);
    int* btot     = (int*)(ws + 103200768);
    int* boffs    = (int*)(ws + 103203896);
    int* offs     = (int*)(ws + 103207040);
    u16* BT1      = (u16*)(ws + 105207056);
    if (ws_size < 105452816) return;  // fail visibly

    const int* src = ei;
    const int* dst = ei + N_EDGES;

    hipMemsetAsync(d_out, 0, 2 * sizeof(float), stream);

    // ---- two-level bucket sort into (dst,rel) segment order
    bucket_hist<<<NWG1, 256, 0, stream>>>(dst, hist);
    col_scan<<<NB, 64, 0, stream>>>(hist, btot);
    btot_scan<<<1, 64, 0, stream>>>(btot, boffs, offs);
    bucket_scatter<<<NWG1, 256, 0, stream>>>(src, dst, et, hist, boffs, bucketed);
    seg_sort<<<NB, 256, 0, stream>>>(bucketed, boffs, offs, ssrc);

    // ---- pack layer-1 weights to BT1 (bf16, [384][256])
    build_bt<<<(384 * EMB + 255) / 256, 256, 0, stream>>>(W1, root1, EMB, BT1);

    // ---- Layer 1: transform-first (256 -> 384, double-buffered), aggregate
    gemm_db<EMB><<<782, 512, 0, stream>>>(uf, BT1, h_all);
    agg_rl<true><<<25000, 256, 0, stream>>>(h_all, ssrc, offs, b1, xbuf);

    // ---- Layer 2: slot-based aggregate-first (only nodes the loss reads)
    agg_mm2<<<1024, 1024, 0, stream>>>(xbuf, ssrc, offs, bill, u1, u2,
                                       W2, root2, b2, semb);

    // ---- Merge MLP + BCE + accuracy
    loss_kernel<<<1024, 256, 0, stream>>>(semb, m1w, m1b, m2w, m2b, out);
}